// Round 8
// baseline (1467.948 us; speedup 1.0000x reference)
//
#include <hip/hip_runtime.h>
#include <cstdint>
#include <cstddef>

#define P_TOT 114688   // N*H*W = 4*128*224
#define W_IMG 224
#define H_IMG 128
#define WP 228         // padded row width (1 left, 3 right)
#define HP 130         // padded rows (1 top, 1 bottom)

typedef _Float16 f16;
typedef __attribute__((ext_vector_type(8))) _Float16 f16x8;
typedef __attribute__((ext_vector_type(4))) _Float16 f16x4;
typedef __attribute__((ext_vector_type(4))) float f32x4;

#define WAITVM(N) asm volatile("s_waitcnt vmcnt(" #N ")" ::: "memory")

__device__ __forceinline__ void barrier_sync() {
  asm volatile("" ::: "memory");
  __builtin_amdgcn_s_barrier();
  asm volatile("" ::: "memory");
}

__device__ __forceinline__ void gload16(const void* g, void* l) {
  __builtin_amdgcn_global_load_lds((const __attribute__((address_space(1))) void*)g,
                                   (__attribute__((address_space(3))) void*)l, 16, 0, 0);
}

__device__ __forceinline__ size_t pad_px(int n, int h, int w) {
  return ((size_t)(n * HP + h + 1)) * WP + (w + 1);
}

// ---------------- zero the halo pixels of a padded slab --------------------------
__global__ void k_halo(f16* __restrict__ slab, int CS) {
  int c8n = CS >> 3;
  int tid = blockIdx.x * 256 + threadIdx.x;
  int c8 = tid % c8n;
  int rest = tid / c8n;
  if (rest >= 4 * 968) return;
  int n = rest / 968, i = rest % 968;
  int h, w;
  if (i < 456) { h = (i < 228) ? 0 : 129; w = i % 228; }
  else { int j = i - 456; h = 1 + (j >> 2); int k = j & 3; w = (k == 0) ? 0 : (224 + k); }
  size_t pp = ((size_t)(n * HP + h)) * WP + w;
  *(f16x8*)(slab + pp * CS + c8 * 8) = (f16x8){0, 0, 0, 0, 0, 0, 0, 0};
}

// ---------------- pack input: fp32 NCHW -> fp16 padded-NHWC, chunk-swizzled ------
// stored slot = true_chunk ^ ((w>>1)&3) within each 32-ch group
__global__ void k_pack_x(const float* __restrict__ x, f16* __restrict__ xb) {
  int tid = threadIdx.x;
  int pw  = tid & 15;
  int c8  = tid >> 4;                 // 0..31
  int p   = blockIdx.x * 16 + pw;     // grid = P_TOT/16
  int w   = p % W_IMG;
  int h   = (p / W_IMG) % H_IMG;
  int n   = p / (H_IMG * W_IMG);
  const float* src = x + ((size_t)(n * 256 + c8 * 8) * H_IMG + h) * W_IMG + w;
  f16x8 v;
#pragma unroll
  for (int j = 0; j < 8; j++) v[j] = (f16)src[(size_t)j * (H_IMG * W_IMG)];
  int c8s = (c8 & ~3) | ((c8 ^ (w >> 1)) & 3);
  *(f16x8*)(xb + pad_px(n, h, w) * 256 + c8s * 8) = v;
}

// ---------------- pack weights into [q][OT][32] (q = kk*CC+c), swizzled by o -----
__global__ void k_pack_w(const float* __restrict__ wa, const float* __restrict__ wb,
                         f16* __restrict__ dst, int mode, int OT, int CS,
                         int Coh, int Cih, int total) {
  int gid = blockIdx.x * 256 + threadIdx.x;
  if (gid >= total) return;
  int j  = gid & 31;
  int t1 = gid >> 5;
  int o  = t1 % OT;
  int t2 = t1 / OT;
  int CCc = CS >> 5;
  int cc = t2 % CCc;
  int kk = t2 / CCc;
  int chunkT = ((j >> 3) ^ (o >> 1)) & 3;   // stored slot holds true chunk slot^key
  int is = cc * 32 + chunkT * 8 + (j & 7);
  float val = 0.f;
  if (mode == 0) {
    val = (o < Coh) ? wa[((size_t)o * Cih + is) * 9 + kk]
                    : wb[((size_t)(o - Coh) * Cih + is) * 9 + kk];
  } else if (mode == 1) {
    if (o < Coh) {
      val = (is < Cih) ? wa[((size_t)o * Cih + is) * 9 + kk]
                       : -wb[((size_t)o * Cih + (is - Cih)) * 9 + kk];
    } else {
      int oo = o - Coh;
      val = (is < Cih) ? wb[((size_t)oo * Cih + is) * 9 + kk]
                       : wa[((size_t)oo * Cih + (is - Cih)) * 9 + kk];
    }
  } else {
    if (o == 0)      val = wa[(size_t)is * 9 + kk];
    else if (o == 1) val = wb[(size_t)is * 9 + kk];
    else if (o == 2) val = wb[(size_t)(96 + is) * 9 + kk];
  }
  dst[gid] = (f16)val;
}

// -------- implicit-GEMM conv: ring-3 LDS, frag-read one chunk ahead -------------
template<int BM, int OT, int CS, int WM, int WN, bool HEAD>
__launch_bounds__(WM * WN * 64, HEAD ? 1 : 2)
__global__ void k_gemm(const f16* __restrict__ xb, const f16* __restrict__ Apack,
                       f16* __restrict__ y, float* __restrict__ outh,
                       const float* __restrict__ bcp, const float* __restrict__ bgp,
                       float* __restrict__ sums, float* __restrict__ sumsq) {
  constexpr int NT = WM * WN * 64;
  constexpr int NWV = NT / 64;
  constexpr int CC = CS / 32;
  constexpr int MF = BM / (WM * 16);       // 3
  constexpr int NF = 224 / (WN * 16);      // 7
  constexpr int NCH = 9 * CC;              // total K chunks of 32
  constexpr int TILE1 = (BM + 224) * 32;   // f16 per chunk buffer (A then B)
  constexpr int ACH = BM / 16;             // A 1KB-chunks
  constexpr int TCH = ACH + 14;            // 1KB-chunks per buffer
  constexpr int NBUF = HEAD ? 2 : 3;
  static_assert(HEAD || (TCH % NWV == 0 && TCH / NWV == 5), "vmcnt math: 5 loads/thread/stage");
  __shared__ __align__(16) f16 lds[NBUF][TILE1];

  constexpr int NOT = OT / BM;
  constexpr int nwg = NOT * 512;
  int bid = blockIdx.x;
  int swz = (bid & 7) * (nwg >> 3) + (bid >> 3);  // XCD swizzle (nwg % 8 == 0)
  const int ot = swz % NOT;                        // ot fastest -> same-B blocks adjacent
  const int rq = swz / NOT;
  const int n = rq >> 7;
  const int h = rq & 127;
  const int tid  = threadIdx.x;
  const int lane = tid & 63;
  const int wv   = tid >> 6;
  const int wm   = wv % WM;
  const int wn   = wv / WM;
  const int obase  = wm * (MF * 16);
  const int wnbase = wn * (NF * 16);
  const int l15 = lane & 15;
  const int lhi = lane >> 4;
  // A frag: row stride 64B; slot = lhi ^ ((row>>1)&3) -> <=2-way bank aliasing (free)
  const int aoff = l15 * 64 + (((lhi ^ (l15 >> 1)) & 3) << 4);

  f32x4 acc[MF][NF];
#pragma unroll
  for (int mi = 0; mi < MF; mi++)
#pragma unroll
    for (int ni = 0; ni < NF; ni++) acc[mi][ni] = (f32x4){0.f, 0.f, 0.f, 0.f};

  // hoisted per-thread staging bases (branch-free: halo pre-zeroed)
  const char* abase = (const char*)Apack + (size_t)ot * BM * 64 + lane * 16;
  const char* bbase = (const char*)xb +
      (pad_px(n, h, 0) + (lane >> 2)) * (size_t)(CS * 2) + (lane & 3) * 16;

  auto stage1 = [&](char* base, int q) {
    const int kk = q / CC, c = q % CC;
    const int doff = (kk / 3 - 1) * WP + (kk % 3 - 1);
    const char* asrc = abase + (size_t)q * (OT * 64);
    const char* bsrc = bbase + doff * (CS * 2) + c * 64;
#pragma unroll
    for (int ck = wv; ck < TCH; ck += NWV) {
      char* dst = base + ck * 1024;           // wave-uniform
      if (ck < ACH) gload16(asrc + ck * 1024, dst);
      else          gload16(bsrc + (size_t)(ck - ACH) * (16 * CS * 2), dst);
    }
  };

  // issue the 10 fragment ds_reads for chunk q from `base` into (af,bfr)
  auto read_frags = [&](const char* base, int q, f16x8* af, f16x8* bfr) {
    const int dw = (q / CC) % 3 - 1;
    const char* Ab = base;
    const char* Bb = base + BM * 64;
#pragma unroll
    for (int mi = 0; mi < MF; mi++)
      af[mi] = *(const f16x8*)(Ab + (obase + mi * 16) * 64 + aoff);
#pragma unroll
    for (int ni = 0; ni < NF; ni++) {
      int px = wnbase + ni * 16 + l15;
      int sw = ((lhi ^ ((px + dw) >> 1)) & 3) << 4;
      bfr[ni] = *(const f16x8*)(Bb + px * 64 + sw);
    }
  };

  auto mfma21 = [&](const f16x8* af, const f16x8* bfr) {
    __builtin_amdgcn_s_setprio(1);
#pragma unroll
    for (int mi = 0; mi < MF; mi++)
#pragma unroll
      for (int ni = 0; ni < NF; ni++)
        acc[mi][ni] = __builtin_amdgcn_mfma_f32_16x16x32_f16(af[mi], bfr[ni], acc[mi][ni], 0, 0, 0);
    __builtin_amdgcn_s_setprio(0);
  };

  if constexpr (!HEAD) {
    f16x8 afA[MF], bfA[NF], afB[MF], bfB[NF];
    // prologue: stage chunks 0,1; read frags0 into set A
    stage1((char*)&lds[0][0], 0);
    stage1((char*)&lds[1][0], 1);
    WAITVM(5);            // chunk0 staged (chunk1 still in flight)
    barrier_sync();
    read_frags((const char*)&lds[0][0], 0, afA, bfA);
    for (int t = 0; t < NCH; t += 2) {
      // ---- sub-iter t: compute set A, prefetch frags t+1 -> set B
      if (t + 2 < NCH) { stage1((char*)&lds[(t + 2) % 3][0], t + 2); WAITVM(5); }
      else if (t + 1 < NCH) { WAITVM(0); }
      if (t + 1 < NCH) {
        barrier_sync();                         // buf[t+1] visible
        read_frags((const char*)&lds[(t + 1) % 3][0], t + 1, afB, bfB);
        __builtin_amdgcn_sched_group_barrier(0x100, MF + NF, 0);  // DS_READ first
        __builtin_amdgcn_sched_group_barrier(0x008, MF * NF, 0);  // then MFMA
      }
      mfma21(afA, bfA);
      if (t + 1 < NCH) barrier_sync();          // buf[t] dead -> restageable
      // ---- sub-iter t+1: compute set B, prefetch frags t+2 -> set A
      if (t + 1 < NCH) {
        if (t + 3 < NCH) { stage1((char*)&lds[(t + 3) % 3][0], t + 3); WAITVM(5); }
        else if (t + 2 < NCH) { WAITVM(0); }
        if (t + 2 < NCH) {
          barrier_sync();
          read_frags((const char*)&lds[(t + 2) % 3][0], t + 2, afA, bfA);
          __builtin_amdgcn_sched_group_barrier(0x100, MF + NF, 0);
          __builtin_amdgcn_sched_group_barrier(0x008, MF * NF, 0);
        }
        mfma21(afB, bfB);
        if (t + 2 < NCH) barrier_sync();
      }
    }
  } else {
    f16x8 afA[MF], bfA[NF];
    stage1((char*)&lds[0][0], 0);
    __syncthreads();
    int buf = 0;
    for (int t = 0; t < NCH; ++t) {
      if (t + 1 < NCH) stage1((char*)&lds[buf ^ 1][0], t + 1);
      read_frags((const char*)&lds[buf][0], t, afA, bfA);
      mfma21(afA, bfA);
      __syncthreads();
      buf ^= 1;
    }
  }

  const size_t prow = pad_px(n, h, 0);
  if constexpr (!HEAD) {
    // store fp16 padded-NHWC output
#pragma unroll
    for (int mi = 0; mi < MF; mi++) {
#pragma unroll
      for (int ni = 0; ni < NF; ni++) {
        int o = obase + mi * 16 + lhi * 4;
        int w = wnbase + ni * 16 + l15;
        f16x4 v4;
#pragma unroll
        for (int j = 0; j < 4; j++) v4[j] = (f16)acc[mi][ni][j];
        *(f16x4*)(y + (prow + w) * OT + ot * BM + o) = v4;
      }
    }
    // fused BN stats: per-channel sum / sumsq partials
    float sv[MF][4], qv[MF][4];
#pragma unroll
    for (int mi = 0; mi < MF; mi++)
#pragma unroll
      for (int j = 0; j < 4; j++) {
        float s = 0.f, q = 0.f;
#pragma unroll
        for (int ni = 0; ni < NF; ni++) {
          float v = acc[mi][ni][j];
          s += v; q += v * v;
        }
        sv[mi][j] = s; qv[mi][j] = q;
      }
#pragma unroll
    for (int m = 1; m < 16; m <<= 1) {
#pragma unroll
      for (int mi = 0; mi < MF; mi++)
#pragma unroll
        for (int j = 0; j < 4; j++) {
          sv[mi][j] += __shfl_xor(sv[mi][j], m);
          qv[mi][j] += __shfl_xor(qv[mi][j], m);
        }
    }
    if (l15 == 0) {
#pragma unroll
      for (int mi = 0; mi < MF; mi++)
#pragma unroll
        for (int j = 0; j < 4; j++) {
          int ch = ot * BM + obase + mi * 16 + lhi * 4 + j;
          atomicAdd(&sums[ch], sv[mi][j]);
          atomicAdd(&sumsq[ch], qv[mi][j]);
        }
    }
  } else {
    if (lhi == 0) {
      float b0 = bcp[0], b1 = bgp[0], b2 = bgp[1];
#pragma unroll
      for (int ni = 0; ni < NF; ni++) {
        int w = wnbase + ni * 16 + l15;
        float c0 = acc[0][ni][0] + b0;
        c0 = 1.f / (1.f + expf(-c0));
        float c1 = acc[0][ni][1] + b1;
        float c2 = acc[0][ni][2] + b2;
        outh[((size_t)(n * 3 + 0) * H_IMG + h) * W_IMG + w] = c0;
        outh[((size_t)(n * 3 + 1) * H_IMG + h) * W_IMG + w] = c1;
        outh[((size_t)(n * 3 + 2) * H_IMG + h) * W_IMG + w] = c2;
      }
    }
  }
}

// ---------------- BN coefficient recompute (fused into consumers) ---------------
template<int O>
__device__ __forceinline__ void bn_coef(const float* __restrict__ sums,
                                        const float* __restrict__ sumsq,
                                        const float* __restrict__ g,
                                        const float* __restrict__ b,
                                        float* sc, float* sh, int tid, int nt) {
  const float inv = 1.0f / (float)P_TOT;
  for (int t = tid; t < O; t += nt) {
    float mean = sums[t] * inv;
    float var  = fmaxf(sumsq[t] * inv - mean * mean, 0.f);
    int gi = (t < O / 2) ? t : (t - O / 2);
    float s = g[gi] * rsqrtf(var + 1e-5f);
    sc[t] = s;
    sh[t] = b[gi] - mean * s;
  }
}

// ---------------- in-place BN + ReLU + chunk-swizzle (finalize fused) -----------
template<int O>
__global__ void k_packip(f16* __restrict__ y,
                         const float* __restrict__ sums, const float* __restrict__ sumsq,
                         const float* __restrict__ g, const float* __restrict__ b) {
  __shared__ float sc[O], sh[O];
  bn_coef<O>(sums, sumsq, g, b, sc, sh, threadIdx.x, 256);
  __syncthreads();
  constexpr int G32 = O / 32;
  int gid = blockIdx.x * 256 + threadIdx.x;
  if (gid >= P_TOT * G32) return;
  int gg = gid % G32;
  int p = gid / G32;
  int w = p % W_IMG;
  int hh = (p / W_IMG) % H_IMG;
  int nn = p / (W_IMG * H_IMG);
  f16* base = y + pad_px(nn, hh, w) * O + gg * 32;
  f16x8 in[4];
#pragma unroll
  for (int ch = 0; ch < 4; ch++) in[ch] = *(const f16x8*)(base + ch * 8);
  int sw = (w >> 1) & 3;
  f16x8 outv[4];
#pragma unroll
  for (int ch = 0; ch < 4; ch++) {
#pragma unroll
    for (int j = 0; j < 8; j++) {
      int cdx = gg * 32 + ch * 8 + j;
      float f = fmaxf(fmaf((float)in[ch][j], sc[cdx], sh[cdx]), 0.f);
      outv[ch][j] = (f16)f;
    }
  }
#pragma unroll
  for (int ch = 0; ch < 4; ch++) *(f16x8*)(base + ((ch ^ sw) & 3) * 8) = outv[ch];
}

// ---------------- BN(L4) + ReLU + complex magnitude -> 96ch swizzled ------------
__global__ void k_mag(const f16* __restrict__ y,
                      const float* __restrict__ sums, const float* __restrict__ sumsq,
                      const float* __restrict__ g, const float* __restrict__ b,
                      f16* __restrict__ mg) {
  __shared__ float sc[192], sh[192];
  bn_coef<192>(sums, sumsq, g, b, sc, sh, threadIdx.x, 256);
  __syncthreads();
  int gid = blockIdx.x * 256 + threadIdx.x;
  if (gid >= P_TOT * 12) return;
  int c8 = gid % 12;
  int p  = gid / 12;
  int w  = p % W_IMG;
  int hh = (p / W_IMG) % H_IMG;
  int nn = p / (W_IMG * H_IMG);
  size_t pp = pad_px(nn, hh, w);
  f16x8 r8 = *(const f16x8*)(y + pp * 192 + c8 * 8);
  f16x8 i8 = *(const f16x8*)(y + pp * 192 + 96 + c8 * 8);
  f16x8 outv;
#pragma unroll
  for (int j = 0; j < 8; j++) {
    int cdx = c8 * 8 + j;
    float rr = fmaxf(fmaf((float)r8[j], sc[cdx], sh[cdx]), 0.f);
    float ii = fmaxf(fmaf((float)i8[j], sc[96 + cdx], sh[96 + cdx]), 0.f);
    outv[j] = (f16)sqrtf(rr * rr + ii * ii);
  }
  int c8s = (c8 & ~3) | ((c8 ^ (w >> 1)) & 3);
  *(f16x8*)(mg + pp * 96 + c8s * 8) = outv;
}

// ------------------------------------------------------------------------------
extern "C" void kernel_launch(void* const* d_in, const int* in_sizes, int n_in,
                              void* d_out, int out_size, void* d_ws, size_t ws_size,
                              hipStream_t stream) {
  const float* x   = (const float*)d_in[0];
  const float* w1r = (const float*)d_in[1];
  const float* w1i = (const float*)d_in[2];
  const float* g1  = (const float*)d_in[3];
  const float* b1  = (const float*)d_in[4];
  const float* w2r = (const float*)d_in[5];
  const float* w2i = (const float*)d_in[6];
  const float* g2  = (const float*)d_in[7];
  const float* b2  = (const float*)d_in[8];
  const float* w3r = (const float*)d_in[9];
  const float* w3i = (const float*)d_in[10];
  const float* g3  = (const float*)d_in[11];
  const float* b3  = (const float*)d_in[12];
  const float* w4r = (const float*)d_in[13];
  const float* w4i = (const float*)d_in[14];
  const float* g4  = (const float*)d_in[15];
  const float* b4  = (const float*)d_in[16];
  const float* wc  = (const float*)d_in[17];
  const float* bcp = (const float*)d_in[18];
  const float* wg  = (const float*)d_in[19];
  const float* bgp = (const float*)d_in[20];
  float* out = (float*)d_out;

  char* ws = (char*)d_ws;
  if (ws_size < 137500000ULL) return;

  auto S  = [&](int L) { return (float*)(ws + 16384 + L * 4096); };
  auto Q  = [&](int L) { return (float*)(ws + 16384 + L * 4096) + 512; };
  f16* A1 = (f16*)(ws + 65536);
  f16* A2 = (f16*)(ws + 1392640);
  f16* A3 = (f16*)(ws + 2387968);
  f16* A4 = (f16*)(ws + 3051520);
  f16* AH = (f16*)(ws + 3715072);
  f16* SLA = (f16*)(ws + 4194304);     // padded slab A
  f16* SLB = (f16*)(ws + 65011712);    // padded slab B

  hipMemsetAsync(d_ws, 0, 49152, stream);  // stats sums

  auto halo_grid = [](int CS) { return (4 * 968 * (CS / 8) + 255) / 256; };

  k_halo<<<halo_grid(256), 256, 0, stream>>>(SLA, 256);
  k_pack_x<<<P_TOT / 16, 512, 0, stream>>>(x, SLA);
  k_pack_w<<<(663552 + 255) / 256, 256, 0, stream>>>(w1r, w1i, A1, 0, 288, 256, 144, 256, 663552);
  k_pack_w<<<(497664 + 255) / 256, 256, 0, stream>>>(w2r, w2i, A2, 1, 192, 288, 96, 144, 497664);
  k_pack_w<<<(331776 + 255) / 256, 256, 0, stream>>>(w3r, w3i, A3, 1, 192, 192, 96, 96, 331776);
  k_pack_w<<<(331776 + 255) / 256, 256, 0, stream>>>(w4r, w4i, A4, 1, 192, 192, 96, 96, 331776);
  k_pack_w<<<(13824 + 255) / 256, 256, 0, stream>>>(wc, wg, AH, 2, 16, 96, 0, 96, 13824);
  k_halo<<<halo_grid(288), 256, 0, stream>>>(SLB, 288);

  // L1: 256 -> 288  (read SLA/256, write SLB/288)
  k_gemm<96, 288, 256, 2, 2, false><<<1536, 256, 0, stream>>>(SLA, A1, SLB, nullptr, nullptr, nullptr, S(0), Q(0));
  k_packip<288><<<P_TOT * 9 / 256, 256, 0, stream>>>(SLB, S(0), Q(0), g1, b1);
  k_halo<<<halo_grid(192), 256, 0, stream>>>(SLA, 192);

  // L2: 288 -> 192  (read SLB/288, write SLA/192)
  k_gemm<96, 192, 288, 2, 2, false><<<1024, 256, 0, stream>>>(SLB, A2, SLA, nullptr, nullptr, nullptr, S(1), Q(1));
  k_packip<192><<<P_TOT * 6 / 256, 256, 0, stream>>>(SLA, S(1), Q(1), g2, b2);
  k_halo<<<halo_grid(192), 256, 0, stream>>>(SLB, 192);

  // L3: 192 -> 192  (read SLA/192, write SLB/192)
  k_gemm<96, 192, 192, 2, 2, false><<<1024, 256, 0, stream>>>(SLA, A3, SLB, nullptr, nullptr, nullptr, S(2), Q(2));
  k_packip<192><<<P_TOT * 6 / 256, 256, 0, stream>>>(SLB, S(2), Q(2), g3, b3);

  // L4: 192 -> 192  (read SLB/192, write SLA/192; SLA halo already zeroed at 192 geom)
  k_gemm<96, 192, 192, 2, 2, false><<<1024, 256, 0, stream>>>(SLB, A4, SLA, nullptr, nullptr, nullptr, S(3), Q(3));
  k_halo<<<halo_grid(96), 256, 0, stream>>>(SLB, 96);

  // BN+ReLU+magnitude -> 96ch head input (read SLA/192, write SLB/96)
  k_mag<<<P_TOT * 12 / 256, 256, 0, stream>>>(SLA, S(3), Q(3), g4, b4, SLB);

  // head: 96 -> 3 (sigmoid on ch0), writes NCHW fp32 output
  k_gemm<16, 16, 96, 1, 2, true><<<512, 128, 0, stream>>>(SLB, AH, nullptr, out, bcp, bgp, nullptr, nullptr);

  (void)in_sizes; (void)n_in; (void)out_size;
}

// Round 10
// 1009.029 us; speedup vs baseline: 1.4548x; 1.4548x over previous
//
#include <hip/hip_runtime.h>
#include <cstdint>
#include <cstddef>

#define P_TOT 114688   // N*H*W = 4*128*224
#define W_IMG 224
#define H_IMG 128
#define WP 228         // padded row width (1 left, 3 right)
#define HP 130         // padded rows (1 top, 1 bottom)

typedef _Float16 f16;
typedef __attribute__((ext_vector_type(8))) _Float16 f16x8;
typedef __attribute__((ext_vector_type(4))) _Float16 f16x4;
typedef __attribute__((ext_vector_type(4))) float f32x4;

#define WAITVM(N) asm volatile("s_waitcnt vmcnt(" #N ")" ::: "memory")
#define WAITLGKM0() asm volatile("s_waitcnt lgkmcnt(0)" ::: "memory")

__device__ __forceinline__ void gload16(const void* g, void* l) {
  __builtin_amdgcn_global_load_lds((const __attribute__((address_space(1))) void*)g,
                                   (__attribute__((address_space(3))) void*)l, 16, 0, 0);
}

__device__ __forceinline__ size_t pad_px(int n, int h, int w) {
  return ((size_t)(n * HP + h + 1)) * WP + (w + 1);
}

// ---------------- zero the halo pixels of a padded slab --------------------------
__global__ void k_halo(f16* __restrict__ slab, int CS) {
  int c8n = CS >> 3;
  int tid = blockIdx.x * 256 + threadIdx.x;
  int c8 = tid % c8n;
  int rest = tid / c8n;
  if (rest >= 4 * 968) return;
  int n = rest / 968, i = rest % 968;
  int h, w;
  if (i < 456) { h = (i < 228) ? 0 : 129; w = i % 228; }
  else { int j = i - 456; h = 1 + (j >> 2); int k = j & 3; w = (k == 0) ? 0 : (224 + k); }
  size_t pp = ((size_t)(n * HP + h)) * WP + w;
  *(f16x8*)(slab + pp * CS + c8 * 8) = (f16x8){0, 0, 0, 0, 0, 0, 0, 0};
}

// ---------------- pack input: fp32 NCHW -> fp16 padded-NHWC, chunk-swizzled ------
// stored slot = true_chunk ^ ((w>>1)&3) within each 32-ch group
__global__ void k_pack_x(const float* __restrict__ x, f16* __restrict__ xb) {
  int tid = threadIdx.x;
  int pw  = tid & 15;
  int c8  = tid >> 4;                 // 0..31
  int p   = blockIdx.x * 16 + pw;     // grid = P_TOT/16
  int w   = p % W_IMG;
  int h   = (p / W_IMG) % H_IMG;
  int n   = p / (H_IMG * W_IMG);
  const float* src = x + ((size_t)(n * 256 + c8 * 8) * H_IMG + h) * W_IMG + w;
  f16x8 v;
#pragma unroll
  for (int j = 0; j < 8; j++) v[j] = (f16)src[(size_t)j * (H_IMG * W_IMG)];
  int c8s = (c8 & ~3) | ((c8 ^ (w >> 1)) & 3);
  *(f16x8*)(xb + pad_px(n, h, w) * 256 + c8s * 8) = v;
}

// ---------------- pack weights into [q][OT][32] (q = kk*CC+c), swizzled by o -----
__global__ void k_pack_w(const float* __restrict__ wa, const float* __restrict__ wb,
                         f16* __restrict__ dst, int mode, int OT, int CS,
                         int Coh, int Cih, int total) {
  int gid = blockIdx.x * 256 + threadIdx.x;
  if (gid >= total) return;
  int j  = gid & 31;
  int t1 = gid >> 5;
  int o  = t1 % OT;
  int t2 = t1 / OT;
  int CCc = CS >> 5;
  int cc = t2 % CCc;
  int kk = t2 / CCc;
  int chunkT = ((j >> 3) ^ (o >> 1)) & 3;   // stored slot holds true chunk slot^key
  int is = cc * 32 + chunkT * 8 + (j & 7);
  float val = 0.f;
  if (mode == 0) {
    val = (o < Coh) ? wa[((size_t)o * Cih + is) * 9 + kk]
                    : wb[((size_t)(o - Coh) * Cih + is) * 9 + kk];
  } else if (mode == 1) {
    if (o < Coh) {
      val = (is < Cih) ? wa[((size_t)o * Cih + is) * 9 + kk]
                       : -wb[((size_t)o * Cih + (is - Cih)) * 9 + kk];
    } else {
      int oo = o - Coh;
      val = (is < Cih) ? wb[((size_t)oo * Cih + is) * 9 + kk]
                       : wa[((size_t)oo * Cih + (is - Cih)) * 9 + kk];
    }
  } else {
    if (o == 0)      val = wa[(size_t)is * 9 + kk];
    else if (o == 1) val = wb[(size_t)is * 9 + kk];
    else if (o == 2) val = wb[(size_t)(96 + is) * 9 + kk];
  }
  dst[gid] = (f16)val;
}

// -------- implicit-GEMM conv: per-wave private LDS staging, NO block barriers ---
// (HEAD uses the proven block-shared double-buffer + __syncthreads path)
template<int BM, int OT, int CS, int WM, int WN, bool HEAD>
__launch_bounds__(WM * WN * 64)
__global__ void k_gemm(const f16* __restrict__ xb, const f16* __restrict__ Apack,
                       f16* __restrict__ y, float* __restrict__ outh,
                       const float* __restrict__ bcp, const float* __restrict__ bgp,
                       float* __restrict__ sums, float* __restrict__ sumsq) {
  constexpr int NT = WM * WN * 64;
  constexpr int NWV = NT / 64;
  constexpr int CC = CS / 32;
  constexpr int MF = BM / (WM * 16);       // 3 (head: 1)
  constexpr int NF = 224 / (WN * 16);      // 7
  constexpr int NCH = 9 * CC;              // total K chunks of 32
  constexpr int AKB = MF;                  // per-wave A 1KB-chunks
  constexpr int BKB = NF;                  // per-wave B 1KB-chunks
  constexpr int WREG = (AKB + BKB) * 1024; // bytes per wave per buffer
  constexpr int LDS_BYTES = HEAD ? (2 * 15 * 1024) : (2 * NWV * WREG);
  static_assert(HEAD || AKB + BKB == 10, "vmcnt(10) math: 10 loads/thread/stage");
  __shared__ __align__(16) char lds[LDS_BYTES];

  constexpr int NOT = OT / BM;
  constexpr int nwg = NOT * 512;
  int bid = blockIdx.x;
  int swz = (bid & 7) * (nwg >> 3) + (bid >> 3);  // XCD swizzle (nwg % 8 == 0)
  const int ot = swz % NOT;                        // ot fastest -> same-B blocks adjacent
  const int rq = swz / NOT;
  const int n = rq >> 7;
  const int h = rq & 127;
  const int tid  = threadIdx.x;
  const int lane = tid & 63;
  const int wv   = tid >> 6;
  const int wm   = wv % WM;
  const int wn   = wv / WM;
  const int obase  = wm * (MF * 16);
  const int wnbase = wn * (NF * 16);
  const int l15 = lane & 15;
  const int lhi = lane >> 4;
  // A frag slot = lhi ^ ((row>>1)&3); row = 16*even + l15 -> key = (l15>>1)&3
  const int aslot = (((lhi ^ (l15 >> 1)) & 3) << 4);

  f32x4 acc[MF][NF];
#pragma unroll
  for (int mi = 0; mi < MF; mi++)
#pragma unroll
    for (int ni = 0; ni < NF; ni++) acc[mi][ni] = (f32x4){0.f, 0.f, 0.f, 0.f};

  // hoisted per-thread staging bases (branch-free: halo pre-zeroed)
  const char* abase = (const char*)Apack + ((size_t)ot * BM + (HEAD ? 0 : obase)) * 64 + lane * 16;
  const char* bbase = (const char*)xb +
      (pad_px(n, h, 0) + (HEAD ? 0 : wnbase) + (lane >> 2)) * (size_t)(CS * 2) + (lane & 3) * 16;

  auto mfma_cluster = [&](const f16x8* af, const f16x8* bfr) {
    __builtin_amdgcn_s_setprio(1);
#pragma unroll
    for (int mi = 0; mi < MF; mi++)
#pragma unroll
      for (int ni = 0; ni < NF; ni++)
        acc[mi][ni] = __builtin_amdgcn_mfma_f32_16x16x32_f16(af[mi], bfr[ni], acc[mi][ni], 0, 0, 0);
    __builtin_amdgcn_s_setprio(0);
  };

  if constexpr (!HEAD) {
    // ---- barrier-free: each wave stages its own 10KB A+B region, dbuf ----
    auto stage_own = [&](char* wbase, int q) {
      const int kk = q / CC, c = q % CC;
      const int doff = (kk / 3 - 1) * WP + (kk % 3 - 1);
      const char* asrc = abase + (size_t)q * (OT * 64);
      const char* bsrc = bbase + (ptrdiff_t)doff * (CS * 2) + c * 64;
#pragma unroll
      for (int ck = 0; ck < AKB; ck++)
        gload16(asrc + ck * 1024, wbase + ck * 1024);
#pragma unroll
      for (int ck = 0; ck < BKB; ck++)
        gload16(bsrc + (size_t)ck * (16 * CS * 2), wbase + AKB * 1024 + ck * 1024);
    };
    auto read_frags = [&](const char* wbase, int q, f16x8* af, f16x8* bfr) {
      const int dw = (q / CC) % 3 - 1;
#pragma unroll
      for (int mi = 0; mi < MF; mi++)
        af[mi] = *(const f16x8*)(wbase + (mi * 16 + l15) * 64 + aslot);
#pragma unroll
      for (int ni = 0; ni < NF; ni++) {
        int px = wnbase + ni * 16 + l15;
        int sw = ((lhi ^ ((px + dw) >> 1)) & 3) << 4;
        bfr[ni] = *(const f16x8*)(wbase + AKB * 1024 + (ni * 16 + l15) * 64 + sw);
      }
    };
    char* w0 = lds + wv * WREG;
    char* w1 = lds + NWV * WREG + wv * WREG;
    f16x8 af[MF], bfr[NF];
    stage_own(w0, 0);
    stage_own(w1, 1);
    for (int t = 0; t < NCH; ++t) {
      char* wb = (t & 1) ? w1 : w0;
      if (t + 1 < NCH) { WAITVM(10); }
      else             { WAITVM(0); }
      read_frags(wb, t, af, bfr);
      mfma_cluster(af, bfr);
      // all frags consumed -> their ds_reads retired; pin re-stage after
      __builtin_amdgcn_sched_barrier(0);
      WAITLGKM0();
      __builtin_amdgcn_sched_barrier(0);
      if (t + 2 < NCH) stage_own(wb, t + 2);
    }
  } else {
    // ---- block-shared double buffer + __syncthreads (proven) ----
    constexpr int TCH = 1 + 14;             // A 1KB + B 14KB per buffer
    auto stage_blk = [&](char* base, int q) {
      const int kk = q / CC, c = q % CC;
      const int doff = (kk / 3 - 1) * WP + (kk % 3 - 1);
      const char* asrc = abase + (size_t)q * (OT * 64);
      const char* bsrc = bbase + (ptrdiff_t)doff * (CS * 2) + c * 64;
      for (int ck = wv; ck < TCH; ck += NWV) {
        char* dst = base + ck * 1024;
        if (ck < 1) gload16(asrc, dst);
        else        gload16(bsrc + (size_t)(ck - 1) * (16 * CS * 2), dst);
      }
    };
    auto read_frags_blk = [&](const char* base, int q, f16x8* af, f16x8* bfr) {
      const int dw = (q / CC) % 3 - 1;
      af[0] = *(const f16x8*)(base + l15 * 64 + aslot);
#pragma unroll
      for (int ni = 0; ni < NF; ni++) {
        int px = wnbase + ni * 16 + l15;
        int sw = ((lhi ^ ((px + dw) >> 1)) & 3) << 4;
        bfr[ni] = *(const f16x8*)(base + 1024 + px * 64 + sw);
      }
    };
    f16x8 af[MF], bfr[NF];
    stage_blk(lds, 0);
    __syncthreads();
    int buf = 0;
    for (int t = 0; t < NCH; ++t) {
      if (t + 1 < NCH) stage_blk(lds + (buf ^ 1) * 15360, t + 1);
      read_frags_blk(lds + buf * 15360, t, af, bfr);
      mfma_cluster(af, bfr);
      __syncthreads();
      buf ^= 1;
    }
  }

  const size_t prow = pad_px(n, h, 0);
  if constexpr (!HEAD) {
    // store fp16 padded-NHWC output
#pragma unroll
    for (int mi = 0; mi < MF; mi++) {
#pragma unroll
      for (int ni = 0; ni < NF; ni++) {
        int o = obase + mi * 16 + lhi * 4;
        int w = wnbase + ni * 16 + l15;
        f16x4 v4;
#pragma unroll
        for (int j = 0; j < 4; j++) v4[j] = (f16)acc[mi][ni][j];
        *(f16x4*)(y + (prow + w) * OT + ot * BM + o) = v4;
      }
    }
    // fused BN stats: per-channel sum / sumsq partials
    float sv[MF][4], qv[MF][4];
#pragma unroll
    for (int mi = 0; mi < MF; mi++)
#pragma unroll
      for (int j = 0; j < 4; j++) {
        float s = 0.f, q = 0.f;
#pragma unroll
        for (int ni = 0; ni < NF; ni++) {
          float v = acc[mi][ni][j];
          s += v; q += v * v;
        }
        sv[mi][j] = s; qv[mi][j] = q;
      }
#pragma unroll
    for (int m = 1; m < 16; m <<= 1) {
#pragma unroll
      for (int mi = 0; mi < MF; mi++)
#pragma unroll
        for (int j = 0; j < 4; j++) {
          sv[mi][j] += __shfl_xor(sv[mi][j], m);
          qv[mi][j] += __shfl_xor(qv[mi][j], m);
        }
    }
    if (l15 == 0) {
#pragma unroll
      for (int mi = 0; mi < MF; mi++)
#pragma unroll
        for (int j = 0; j < 4; j++) {
          int ch = ot * BM + obase + mi * 16 + lhi * 4 + j;
          atomicAdd(&sums[ch], sv[mi][j]);
          atomicAdd(&sumsq[ch], qv[mi][j]);
        }
    }
  } else {
    if (lhi == 0) {
      float b0 = bcp[0], b1 = bgp[0], b2 = bgp[1];
#pragma unroll
      for (int ni = 0; ni < NF; ni++) {
        int w = wnbase + ni * 16 + l15;
        float c0 = acc[0][ni][0] + b0;
        c0 = 1.f / (1.f + expf(-c0));
        float c1 = acc[0][ni][1] + b1;
        float c2 = acc[0][ni][2] + b2;
        outh[((size_t)(n * 3 + 0) * H_IMG + h) * W_IMG + w] = c0;
        outh[((size_t)(n * 3 + 1) * H_IMG + h) * W_IMG + w] = c1;
        outh[((size_t)(n * 3 + 2) * H_IMG + h) * W_IMG + w] = c2;
      }
    }
  }
}

// ---------------- BN coefficient recompute (fused into consumers) ---------------
template<int O>
__device__ __forceinline__ void bn_coef(const float* __restrict__ sums,
                                        const float* __restrict__ sumsq,
                                        const float* __restrict__ g,
                                        const float* __restrict__ b,
                                        float* sc, float* sh, int tid, int nt) {
  const float inv = 1.0f / (float)P_TOT;
  for (int t = tid; t < O; t += nt) {
    float mean = sums[t] * inv;
    float var  = fmaxf(sumsq[t] * inv - mean * mean, 0.f);
    int gi = (t < O / 2) ? t : (t - O / 2);
    float s = g[gi] * rsqrtf(var + 1e-5f);
    sc[t] = s;
    sh[t] = b[gi] - mean * s;
  }
}

// ---------------- in-place BN + ReLU + chunk-swizzle (finalize fused) -----------
template<int O>
__global__ void k_packip(f16* __restrict__ y,
                         const float* __restrict__ sums, const float* __restrict__ sumsq,
                         const float* __restrict__ g, const float* __restrict__ b) {
  __shared__ float sc[O], sh[O];
  bn_coef<O>(sums, sumsq, g, b, sc, sh, threadIdx.x, 256);
  __syncthreads();
  constexpr int G32 = O / 32;
  int gid = blockIdx.x * 256 + threadIdx.x;
  if (gid >= P_TOT * G32) return;
  int gg = gid % G32;
  int p = gid / G32;
  int w = p % W_IMG;
  int hh = (p / W_IMG) % H_IMG;
  int nn = p / (W_IMG * H_IMG);
  f16* base = y + pad_px(nn, hh, w) * O + gg * 32;
  f16x8 in[4];
#pragma unroll
  for (int ch = 0; ch < 4; ch++) in[ch] = *(const f16x8*)(base + ch * 8);
  int sw = (w >> 1) & 3;
  f16x8 outv[4];
#pragma unroll
  for (int ch = 0; ch < 4; ch++) {
#pragma unroll
    for (int j = 0; j < 8; j++) {
      int cdx = gg * 32 + ch * 8 + j;
      float f = fmaxf(fmaf((float)in[ch][j], sc[cdx], sh[cdx]), 0.f);
      outv[ch][j] = (f16)f;
    }
  }
#pragma unroll
  for (int ch = 0; ch < 4; ch++) *(f16x8*)(base + ((ch ^ sw) & 3) * 8) = outv[ch];
}

// ---------------- BN(L4) + ReLU + complex magnitude -> 96ch swizzled ------------
__global__ void k_mag(const f16* __restrict__ y,
                      const float* __restrict__ sums, const float* __restrict__ sumsq,
                      const float* __restrict__ g, const float* __restrict__ b,
                      f16* __restrict__ mg) {
  __shared__ float sc[192], sh[192];
  bn_coef<192>(sums, sumsq, g, b, sc, sh, threadIdx.x, 256);
  __syncthreads();
  int gid = blockIdx.x * 256 + threadIdx.x;
  if (gid >= P_TOT * 12) return;
  int c8 = gid % 12;
  int p  = gid / 12;
  int w  = p % W_IMG;
  int hh = (p / W_IMG) % H_IMG;
  int nn = p / (W_IMG * H_IMG);
  size_t pp = pad_px(nn, hh, w);
  f16x8 r8 = *(const f16x8*)(y + pp * 192 + c8 * 8);
  f16x8 i8 = *(const f16x8*)(y + pp * 192 + 96 + c8 * 8);
  f16x8 outv;
#pragma unroll
  for (int j = 0; j < 8; j++) {
    int cdx = c8 * 8 + j;
    float rr = fmaxf(fmaf((float)r8[j], sc[cdx], sh[cdx]), 0.f);
    float ii = fmaxf(fmaf((float)i8[j], sc[96 + cdx], sh[96 + cdx]), 0.f);
    outv[j] = (f16)sqrtf(rr * rr + ii * ii);
  }
  int c8s = (c8 & ~3) | ((c8 ^ (w >> 1)) & 3);
  *(f16x8*)(mg + pp * 96 + c8s * 8) = outv;
}

// ------------------------------------------------------------------------------
extern "C" void kernel_launch(void* const* d_in, const int* in_sizes, int n_in,
                              void* d_out, int out_size, void* d_ws, size_t ws_size,
                              hipStream_t stream) {
  const float* x   = (const float*)d_in[0];
  const float* w1r = (const float*)d_in[1];
  const float* w1i = (const float*)d_in[2];
  const float* g1  = (const float*)d_in[3];
  const float* b1  = (const float*)d_in[4];
  const float* w2r = (const float*)d_in[5];
  const float* w2i = (const float*)d_in[6];
  const float* g2  = (const float*)d_in[7];
  const float* b2  = (const float*)d_in[8];
  const float* w3r = (const float*)d_in[9];
  const float* w3i = (const float*)d_in[10];
  const float* g3  = (const float*)d_in[11];
  const float* b3  = (const float*)d_in[12];
  const float* w4r = (const float*)d_in[13];
  const float* w4i = (const float*)d_in[14];
  const float* g4  = (const float*)d_in[15];
  const float* b4  = (const float*)d_in[16];
  const float* wc  = (const float*)d_in[17];
  const float* bcp = (const float*)d_in[18];
  const float* wg  = (const float*)d_in[19];
  const float* bgp = (const float*)d_in[20];
  float* out = (float*)d_out;

  char* ws = (char*)d_ws;
  if (ws_size < 137500000ULL) return;

  auto S  = [&](int L) { return (float*)(ws + 16384 + L * 4096); };
  auto Q  = [&](int L) { return (float*)(ws + 16384 + L * 4096) + 512; };
  f16* A1 = (f16*)(ws + 65536);
  f16* A2 = (f16*)(ws + 1392640);
  f16* A3 = (f16*)(ws + 2387968);
  f16* A4 = (f16*)(ws + 3051520);
  f16* AH = (f16*)(ws + 3715072);
  f16* SLA = (f16*)(ws + 4194304);     // padded slab A
  f16* SLB = (f16*)(ws + 65011712);    // padded slab B

  hipMemsetAsync(d_ws, 0, 49152, stream);  // stats sums

  auto halo_grid = [](int CS) { return (4 * 968 * (CS / 8) + 255) / 256; };

  k_halo<<<halo_grid(256), 256, 0, stream>>>(SLA, 256);
  k_pack_x<<<P_TOT / 16, 512, 0, stream>>>(x, SLA);
  k_pack_w<<<(663552 + 255) / 256, 256, 0, stream>>>(w1r, w1i, A1, 0, 288, 256, 144, 256, 663552);
  k_pack_w<<<(497664 + 255) / 256, 256, 0, stream>>>(w2r, w2i, A2, 1, 192, 288, 96, 144, 497664);
  k_pack_w<<<(331776 + 255) / 256, 256, 0, stream>>>(w3r, w3i, A3, 1, 192, 192, 96, 96, 331776);
  k_pack_w<<<(331776 + 255) / 256, 256, 0, stream>>>(w4r, w4i, A4, 1, 192, 192, 96, 96, 331776);
  k_pack_w<<<(13824 + 255) / 256, 256, 0, stream>>>(wc, wg, AH, 2, 16, 96, 0, 96, 13824);
  k_halo<<<halo_grid(288), 256, 0, stream>>>(SLB, 288);

  // L1: 256 -> 288  (read SLA/256, write SLB/288)
  k_gemm<96, 288, 256, 2, 2, false><<<1536, 256, 0, stream>>>(SLA, A1, SLB, nullptr, nullptr, nullptr, S(0), Q(0));
  k_packip<288><<<P_TOT * 9 / 256, 256, 0, stream>>>(SLB, S(0), Q(0), g1, b1);
  k_halo<<<halo_grid(192), 256, 0, stream>>>(SLA, 192);

  // L2: 288 -> 192  (read SLB/288, write SLA/192)
  k_gemm<96, 192, 288, 2, 2, false><<<1024, 256, 0, stream>>>(SLB, A2, SLA, nullptr, nullptr, nullptr, S(1), Q(1));
  k_packip<192><<<P_TOT * 6 / 256, 256, 0, stream>>>(SLA, S(1), Q(1), g2, b2);
  k_halo<<<halo_grid(192), 256, 0, stream>>>(SLB, 192);

  // L3: 192 -> 192  (read SLA/192, write SLB/192)
  k_gemm<96, 192, 192, 2, 2, false><<<1024, 256, 0, stream>>>(SLA, A3, SLB, nullptr, nullptr, nullptr, S(2), Q(2));
  k_packip<192><<<P_TOT * 6 / 256, 256, 0, stream>>>(SLB, S(2), Q(2), g3, b3);

  // L4: 192 -> 192  (read SLB/192, write SLA/192; SLA halo already zeroed at 192 geom)
  k_gemm<96, 192, 192, 2, 2, false><<<1024, 256, 0, stream>>>(SLB, A4, SLA, nullptr, nullptr, nullptr, S(3), Q(3));
  k_halo<<<halo_grid(96), 256, 0, stream>>>(SLB, 96);

  // BN+ReLU+magnitude -> 96ch head input (read SLA/192, write SLB/96)
  k_mag<<<P_TOT * 12 / 256, 256, 0, stream>>>(SLA, S(3), Q(3), g4, b4, SLB);

  // head: 96 -> 3 (sigmoid on ch0), writes NCHW fp32 output
  k_gemm<16, 16, 96, 1, 2, true><<<512, 128, 0, stream>>>(SLB, AH, nullptr, out, bcp, bgp, nullptr, nullptr);

  (void)in_sizes; (void)n_in; (void)out_size;
}

// Round 11
// 941.285 us; speedup vs baseline: 1.5595x; 1.0720x over previous
//
#include <hip/hip_runtime.h>
#include <cstdint>
#include <cstddef>

#define P_TOT 114688   // N*H*W = 4*128*224
#define W_IMG 224
#define H_IMG 128
#define WP 228         // padded row width (1 left, 3 right)
#define HP 130         // padded rows (1 top, 1 bottom)

typedef _Float16 f16;
typedef __attribute__((ext_vector_type(8))) _Float16 f16x8;
typedef __attribute__((ext_vector_type(4))) _Float16 f16x4;
typedef __attribute__((ext_vector_type(4))) float f32x4;

#define WAITVM(N) asm volatile("s_waitcnt vmcnt(" #N ")" ::: "memory")
#define WAITLGKM0() asm volatile("s_waitcnt lgkmcnt(0)" ::: "memory")

__device__ __forceinline__ void barrier_sync() {
  asm volatile("" ::: "memory");
  __builtin_amdgcn_s_barrier();
  asm volatile("" ::: "memory");
}

__device__ __forceinline__ void gload16(const void* g, void* l) {
  __builtin_amdgcn_global_load_lds((const __attribute__((address_space(1))) void*)g,
                                   (__attribute__((address_space(3))) void*)l, 16, 0, 0);
}

__device__ __forceinline__ size_t pad_px(int n, int h, int w) {
  return ((size_t)(n * HP + h + 1)) * WP + (w + 1);
}

// ---------------- zero the halo pixels of a padded slab --------------------------
__global__ void k_halo(f16* __restrict__ slab, int CS) {
  int c8n = CS >> 3;
  int tid = blockIdx.x * 256 + threadIdx.x;
  int c8 = tid % c8n;
  int rest = tid / c8n;
  if (rest >= 4 * 968) return;
  int n = rest / 968, i = rest % 968;
  int h, w;
  if (i < 456) { h = (i < 228) ? 0 : 129; w = i % 228; }
  else { int j = i - 456; h = 1 + (j >> 2); int k = j & 3; w = (k == 0) ? 0 : (224 + k); }
  size_t pp = ((size_t)(n * HP + h)) * WP + w;
  *(f16x8*)(slab + pp * CS + c8 * 8) = (f16x8){0, 0, 0, 0, 0, 0, 0, 0};
}

// ---------------- pack input: fp32 NCHW -> fp16 padded-NHWC, chunk-swizzled ------
// stored slot = true_chunk ^ ((w>>1)&3) within each 32-ch group
__global__ void k_pack_x(const float* __restrict__ x, f16* __restrict__ xb) {
  int tid = threadIdx.x;
  int pw  = tid & 15;
  int c8  = tid >> 4;                 // 0..31
  int p   = blockIdx.x * 16 + pw;     // grid = P_TOT/16
  int w   = p % W_IMG;
  int h   = (p / W_IMG) % H_IMG;
  int n   = p / (H_IMG * W_IMG);
  const float* src = x + ((size_t)(n * 256 + c8 * 8) * H_IMG + h) * W_IMG + w;
  f16x8 v;
#pragma unroll
  for (int j = 0; j < 8; j++) v[j] = (f16)src[(size_t)j * (H_IMG * W_IMG)];
  int c8s = (c8 & ~3) | ((c8 ^ (w >> 1)) & 3);
  *(f16x8*)(xb + pad_px(n, h, w) * 256 + c8s * 8) = v;
}

// ---------------- pack weights into [q][OT][32] (q = kk*CC+c), swizzled by o -----
__global__ void k_pack_w(const float* __restrict__ wa, const float* __restrict__ wb,
                         f16* __restrict__ dst, int mode, int OT, int CS,
                         int Coh, int Cih, int total) {
  int gid = blockIdx.x * 256 + threadIdx.x;
  if (gid >= total) return;
  int j  = gid & 31;
  int t1 = gid >> 5;
  int o  = t1 % OT;
  int t2 = t1 / OT;
  int CCc = CS >> 5;
  int cc = t2 % CCc;
  int kk = t2 / CCc;
  int chunkT = ((j >> 3) ^ (o >> 1)) & 3;   // stored slot holds true chunk slot^key
  int is = cc * 32 + chunkT * 8 + (j & 7);
  float val = 0.f;
  if (mode == 0) {
    val = (o < Coh) ? wa[((size_t)o * Cih + is) * 9 + kk]
                    : wb[((size_t)(o - Coh) * Cih + is) * 9 + kk];
  } else if (mode == 1) {
    if (o < Coh) {
      val = (is < Cih) ? wa[((size_t)o * Cih + is) * 9 + kk]
                       : -wb[((size_t)o * Cih + (is - Cih)) * 9 + kk];
    } else {
      int oo = o - Coh;
      val = (is < Cih) ? wb[((size_t)oo * Cih + is) * 9 + kk]
                       : wa[((size_t)oo * Cih + (is - Cih)) * 9 + kk];
    }
  } else {
    if (o == 0)      val = wa[(size_t)is * 9 + kk];
    else if (o == 1) val = wb[(size_t)is * 9 + kk];
    else if (o == 2) val = wb[(size_t)(96 + is) * 9 + kk];
  }
  dst[gid] = (f16)val;
}

// -------- implicit-GEMM conv: ring-4 LDS, reads-before-barrier, vmcnt depth-3 ---
template<int BM, int OT, int CS, int WM, int WN, bool HEAD>
__launch_bounds__(WM * WN * 64)
__global__ void k_gemm(const f16* __restrict__ xb, const f16* __restrict__ Apack,
                       f16* __restrict__ y, float* __restrict__ outh,
                       const float* __restrict__ bcp, const float* __restrict__ bgp,
                       float* __restrict__ sums, float* __restrict__ sumsq) {
  constexpr int NT = WM * WN * 64;
  constexpr int NWV = NT / 64;
  constexpr int CC = CS / 32;
  constexpr int MF = BM / (WM * 16);       // 3 (head: 1)
  constexpr int NF = 224 / (WN * 16);      // 7
  constexpr int NCH = 9 * CC;              // total K chunks of 32
  constexpr int ACH = BM / 16;             // A 1KB-chunks per buffer
  constexpr int TCH = ACH + 14;            // 1KB-chunks per buffer (20 for layers)
  constexpr int TILE1B = TCH * 1024;       // bytes per chunk buffer
  constexpr int LDS_BYTES = HEAD ? (2 * 15 * 1024) : (4 * TILE1B);
  static_assert(HEAD || (TCH % NWV == 0 && TCH / NWV == 5), "vmcnt math: 5 loads/thread/chunk");
  __shared__ __align__(16) char lds[LDS_BYTES];

  constexpr int NOT = OT / BM;
  constexpr int nwg = NOT * 512;
  int bid = blockIdx.x;
  int swz = (bid & 7) * (nwg >> 3) + (bid >> 3);  // XCD swizzle (nwg % 8 == 0)
  const int ot = swz % NOT;                        // ot fastest -> same-B blocks adjacent
  const int rq = swz / NOT;
  const int n = rq >> 7;
  const int h = rq & 127;
  const int tid  = threadIdx.x;
  const int lane = tid & 63;
  const int wv   = tid >> 6;
  const int wm   = wv % WM;
  const int wn   = wv / WM;
  const int obase  = wm * (MF * 16);
  const int wnbase = wn * (NF * 16);
  const int l15 = lane & 15;
  const int lhi = lane >> 4;
  // A frag: row stride 64B; slot = lhi ^ ((row>>1)&3) -> <=2-way bank aliasing (free)
  const int aoff = l15 * 64 + (((lhi ^ (l15 >> 1)) & 3) << 4);

  f32x4 acc[MF][NF];
#pragma unroll
  for (int mi = 0; mi < MF; mi++)
#pragma unroll
    for (int ni = 0; ni < NF; ni++) acc[mi][ni] = (f32x4){0.f, 0.f, 0.f, 0.f};

  // hoisted per-thread staging bases (branch-free: halo pre-zeroed)
  const char* abase = (const char*)Apack + (size_t)ot * BM * 64 + lane * 16;
  const char* bbase = (const char*)xb +
      (pad_px(n, h, 0) + (lane >> 2)) * (size_t)(CS * 2) + (lane & 3) * 16;

  // stage one K-chunk q into a 20KB buffer (5 gloads/thread, block-shared)
  auto stage1 = [&](char* base, int q) {
    const int kk = q / CC, c = q % CC;
    const int doff = (kk / 3 - 1) * WP + (kk % 3 - 1);
    const char* asrc = abase + (size_t)q * (OT * 64);
    const char* bsrc = bbase + (ptrdiff_t)doff * (CS * 2) + c * 64;
#pragma unroll
    for (int ck = wv; ck < TCH; ck += NWV) {
      char* dst = base + ck * 1024;           // wave-uniform
      if (ck < ACH) gload16(asrc + ck * 1024, dst);
      else          gload16(bsrc + (size_t)(ck - ACH) * (16 * CS * 2), dst);
    }
  };

  auto read_frags = [&](const char* base, int q, f16x8* af, f16x8* bfr) {
    const int dw = (q / CC) % 3 - 1;
    const char* Ab = base;
    const char* Bb = base + ACH * 1024;
#pragma unroll
    for (int mi = 0; mi < MF; mi++)
      af[mi] = *(const f16x8*)(Ab + (obase + mi * 16) * 64 + aoff);
#pragma unroll
    for (int ni = 0; ni < NF; ni++) {
      int px = wnbase + ni * 16 + l15;
      int sw = ((lhi ^ ((px + dw) >> 1)) & 3) << 4;
      bfr[ni] = *(const f16x8*)(Bb + px * 64 + sw);
    }
  };

  auto mfma_cluster = [&](const f16x8* af, const f16x8* bfr) {
    __builtin_amdgcn_s_setprio(1);
#pragma unroll
    for (int mi = 0; mi < MF; mi++)
#pragma unroll
      for (int ni = 0; ni < NF; ni++)
        acc[mi][ni] = __builtin_amdgcn_mfma_f32_16x16x32_f16(af[mi], bfr[ni], acc[mi][ni], 0, 0, 0);
    __builtin_amdgcn_s_setprio(0);
  };

  if constexpr (!HEAD) {
    // m201-style schedule on ring-4 chunk buffers:
    //   reads(t) pre-barrier | stage(t+3) | vmcnt confirms t+1 | bar | lgkm0 | MFMA | bar
    f16x8 af[MF], bfr[NF];
    stage1(lds + 0 * TILE1B, 0);
    stage1(lds + 1 * TILE1B, 1);
    stage1(lds + 2 * TILE1B, 2);
    WAITVM(10);               // chunk 0 staged (1,2 in flight)
    barrier_sync();
    for (int t = 0; t < NCH; ++t) {
      read_frags(lds + (t & 3) * TILE1B, t, af, bfr);
      if (t + 3 < NCH) { stage1(lds + ((t + 3) & 3) * TILE1B, t + 3); WAITVM(10); }
      else if (t + 3 == NCH) { WAITVM(5); }
      else if (t + 2 == NCH) { WAITVM(0); }
      barrier_sync();
      WAITLGKM0();
      __builtin_amdgcn_sched_barrier(0);
      mfma_cluster(af, bfr);
      barrier_sync();
    }
  } else {
    // ---- block-shared double buffer + __syncthreads (proven) ----
    constexpr int HTCH = 1 + 14;            // A 1KB + B 14KB per buffer
    auto stage_blk = [&](char* base, int q) {
      const int kk = q / CC, c = q % CC;
      const int doff = (kk / 3 - 1) * WP + (kk % 3 - 1);
      const char* asrc = abase + (size_t)q * (OT * 64);
      const char* bsrc = bbase + (ptrdiff_t)doff * (CS * 2) + c * 64;
      for (int ck = wv; ck < HTCH; ck += NWV) {
        char* dst = base + ck * 1024;
        if (ck < 1) gload16(asrc, dst);
        else        gload16(bsrc + (size_t)(ck - 1) * (16 * CS * 2), dst);
      }
    };
    f16x8 af[MF], bfr[NF];
    stage_blk(lds, 0);
    __syncthreads();
    int buf = 0;
    for (int t = 0; t < NCH; ++t) {
      if (t + 1 < NCH) stage_blk(lds + (buf ^ 1) * 15360, t + 1);
      read_frags(lds + buf * 15360, t, af, bfr);
      mfma_cluster(af, bfr);
      __syncthreads();
      buf ^= 1;
    }
  }

  const size_t prow = pad_px(n, h, 0);
  if constexpr (!HEAD) {
    // store fp16 padded-NHWC output
#pragma unroll
    for (int mi = 0; mi < MF; mi++) {
#pragma unroll
      for (int ni = 0; ni < NF; ni++) {
        int o = obase + mi * 16 + lhi * 4;
        int w = wnbase + ni * 16 + l15;
        f16x4 v4;
#pragma unroll
        for (int j = 0; j < 4; j++) v4[j] = (f16)acc[mi][ni][j];
        *(f16x4*)(y + (prow + w) * OT + ot * BM + o) = v4;
      }
    }
    // fused BN stats: per-channel sum / sumsq partials
    float sv[MF][4], qv[MF][4];
#pragma unroll
    for (int mi = 0; mi < MF; mi++)
#pragma unroll
      for (int j = 0; j < 4; j++) {
        float s = 0.f, q = 0.f;
#pragma unroll
        for (int ni = 0; ni < NF; ni++) {
          float v = acc[mi][ni][j];
          s += v; q += v * v;
        }
        sv[mi][j] = s; qv[mi][j] = q;
      }
#pragma unroll
    for (int m = 1; m < 16; m <<= 1) {
#pragma unroll
      for (int mi = 0; mi < MF; mi++)
#pragma unroll
        for (int j = 0; j < 4; j++) {
          sv[mi][j] += __shfl_xor(sv[mi][j], m);
          qv[mi][j] += __shfl_xor(qv[mi][j], m);
        }
    }
    if (l15 == 0) {
#pragma unroll
      for (int mi = 0; mi < MF; mi++)
#pragma unroll
        for (int j = 0; j < 4; j++) {
          int ch = ot * BM + obase + mi * 16 + lhi * 4 + j;
          atomicAdd(&sums[ch], sv[mi][j]);
          atomicAdd(&sumsq[ch], qv[mi][j]);
        }
    }
  } else {
    if (lhi == 0) {
      float b0 = bcp[0], b1 = bgp[0], b2 = bgp[1];
#pragma unroll
      for (int ni = 0; ni < NF; ni++) {
        int w = wnbase + ni * 16 + l15;
        float c0 = acc[0][ni][0] + b0;
        c0 = 1.f / (1.f + expf(-c0));
        float c1 = acc[0][ni][1] + b1;
        float c2 = acc[0][ni][2] + b2;
        outh[((size_t)(n * 3 + 0) * H_IMG + h) * W_IMG + w] = c0;
        outh[((size_t)(n * 3 + 1) * H_IMG + h) * W_IMG + w] = c1;
        outh[((size_t)(n * 3 + 2) * H_IMG + h) * W_IMG + w] = c2;
      }
    }
  }
}

// ---------------- BN coefficient recompute (fused into consumers) ---------------
template<int O>
__device__ __forceinline__ void bn_coef(const float* __restrict__ sums,
                                        const float* __restrict__ sumsq,
                                        const float* __restrict__ g,
                                        const float* __restrict__ b,
                                        float* sc, float* sh, int tid, int nt) {
  const float inv = 1.0f / (float)P_TOT;
  for (int t = tid; t < O; t += nt) {
    float mean = sums[t] * inv;
    float var  = fmaxf(sumsq[t] * inv - mean * mean, 0.f);
    int gi = (t < O / 2) ? t : (t - O / 2);
    float s = g[gi] * rsqrtf(var + 1e-5f);
    sc[t] = s;
    sh[t] = b[gi] - mean * s;
  }
}

// ---------------- in-place BN + ReLU + chunk-swizzle (finalize fused) -----------
template<int O>
__global__ void k_packip(f16* __restrict__ y,
                         const float* __restrict__ sums, const float* __restrict__ sumsq,
                         const float* __restrict__ g, const float* __restrict__ b) {
  __shared__ float sc[O], sh[O];
  bn_coef<O>(sums, sumsq, g, b, sc, sh, threadIdx.x, 256);
  __syncthreads();
  constexpr int G32 = O / 32;
  int gid = blockIdx.x * 256 + threadIdx.x;
  if (gid >= P_TOT * G32) return;
  int gg = gid % G32;
  int p = gid / G32;
  int w = p % W_IMG;
  int hh = (p / W_IMG) % H_IMG;
  int nn = p / (W_IMG * H_IMG);
  f16* base = y + pad_px(nn, hh, w) * O + gg * 32;
  f16x8 in[4];
#pragma unroll
  for (int ch = 0; ch < 4; ch++) in[ch] = *(const f16x8*)(base + ch * 8);
  int sw = (w >> 1) & 3;
  f16x8 outv[4];
#pragma unroll
  for (int ch = 0; ch < 4; ch++) {
#pragma unroll
    for (int j = 0; j < 8; j++) {
      int cdx = gg * 32 + ch * 8 + j;
      float f = fmaxf(fmaf((float)in[ch][j], sc[cdx], sh[cdx]), 0.f);
      outv[ch][j] = (f16)f;
    }
  }
#pragma unroll
  for (int ch = 0; ch < 4; ch++) *(f16x8*)(base + ((ch ^ sw) & 3) * 8) = outv[ch];
}

// ---------------- BN(L4) + ReLU + complex magnitude -> 96ch swizzled ------------
__global__ void k_mag(const f16* __restrict__ y,
                      const float* __restrict__ sums, const float* __restrict__ sumsq,
                      const float* __restrict__ g, const float* __restrict__ b,
                      f16* __restrict__ mg) {
  __shared__ float sc[192], sh[192];
  bn_coef<192>(sums, sumsq, g, b, sc, sh, threadIdx.x, 256);
  __syncthreads();
  int gid = blockIdx.x * 256 + threadIdx.x;
  if (gid >= P_TOT * 12) return;
  int c8 = gid % 12;
  int p  = gid / 12;
  int w  = p % W_IMG;
  int hh = (p / W_IMG) % H_IMG;
  int nn = p / (W_IMG * H_IMG);
  size_t pp = pad_px(nn, hh, w);
  f16x8 r8 = *(const f16x8*)(y + pp * 192 + c8 * 8);
  f16x8 i8 = *(const f16x8*)(y + pp * 192 + 96 + c8 * 8);
  f16x8 outv;
#pragma unroll
  for (int j = 0; j < 8; j++) {
    int cdx = c8 * 8 + j;
    float rr = fmaxf(fmaf((float)r8[j], sc[cdx], sh[cdx]), 0.f);
    float ii = fmaxf(fmaf((float)i8[j], sc[96 + cdx], sh[96 + cdx]), 0.f);
    outv[j] = (f16)sqrtf(rr * rr + ii * ii);
  }
  int c8s = (c8 & ~3) | ((c8 ^ (w >> 1)) & 3);
  *(f16x8*)(mg + pp * 96 + c8s * 8) = outv;
}

// ------------------------------------------------------------------------------
extern "C" void kernel_launch(void* const* d_in, const int* in_sizes, int n_in,
                              void* d_out, int out_size, void* d_ws, size_t ws_size,
                              hipStream_t stream) {
  const float* x   = (const float*)d_in[0];
  const float* w1r = (const float*)d_in[1];
  const float* w1i = (const float*)d_in[2];
  const float* g1  = (const float*)d_in[3];
  const float* b1  = (const float*)d_in[4];
  const float* w2r = (const float*)d_in[5];
  const float* w2i = (const float*)d_in[6];
  const float* g2  = (const float*)d_in[7];
  const float* b2  = (const float*)d_in[8];
  const float* w3r = (const float*)d_in[9];
  const float* w3i = (const float*)d_in[10];
  const float* g3  = (const float*)d_in[11];
  const float* b3  = (const float*)d_in[12];
  const float* w4r = (const float*)d_in[13];
  const float* w4i = (const float*)d_in[14];
  const float* g4  = (const float*)d_in[15];
  const float* b4  = (const float*)d_in[16];
  const float* wc  = (const float*)d_in[17];
  const float* bcp = (const float*)d_in[18];
  const float* wg  = (const float*)d_in[19];
  const float* bgp = (const float*)d_in[20];
  float* out = (float*)d_out;

  char* ws = (char*)d_ws;
  if (ws_size < 137500000ULL) return;

  auto S  = [&](int L) { return (float*)(ws + 16384 + L * 4096); };
  auto Q  = [&](int L) { return (float*)(ws + 16384 + L * 4096) + 512; };
  f16* A1 = (f16*)(ws + 65536);
  f16* A2 = (f16*)(ws + 1392640);
  f16* A3 = (f16*)(ws + 2387968);
  f16* A4 = (f16*)(ws + 3051520);
  f16* AH = (f16*)(ws + 3715072);
  f16* SLA = (f16*)(ws + 4194304);     // padded slab A
  f16* SLB = (f16*)(ws + 65011712);    // padded slab B

  hipMemsetAsync(d_ws, 0, 49152, stream);  // stats sums

  auto halo_grid = [](int CS) { return (4 * 968 * (CS / 8) + 255) / 256; };

  k_halo<<<halo_grid(256), 256, 0, stream>>>(SLA, 256);
  k_pack_x<<<P_TOT / 16, 512, 0, stream>>>(x, SLA);
  k_pack_w<<<(663552 + 255) / 256, 256, 0, stream>>>(w1r, w1i, A1, 0, 288, 256, 144, 256, 663552);
  k_pack_w<<<(497664 + 255) / 256, 256, 0, stream>>>(w2r, w2i, A2, 1, 192, 288, 96, 144, 497664);
  k_pack_w<<<(331776 + 255) / 256, 256, 0, stream>>>(w3r, w3i, A3, 1, 192, 192, 96, 96, 331776);
  k_pack_w<<<(331776 + 255) / 256, 256, 0, stream>>>(w4r, w4i, A4, 1, 192, 192, 96, 96, 331776);
  k_pack_w<<<(13824 + 255) / 256, 256, 0, stream>>>(wc, wg, AH, 2, 16, 96, 0, 96, 13824);
  k_halo<<<halo_grid(288), 256, 0, stream>>>(SLB, 288);

  // L1: 256 -> 288  (read SLA/256, write SLB/288)
  k_gemm<96, 288, 256, 2, 2, false><<<1536, 256, 0, stream>>>(SLA, A1, SLB, nullptr, nullptr, nullptr, S(0), Q(0));
  k_packip<288><<<P_TOT * 9 / 256, 256, 0, stream>>>(SLB, S(0), Q(0), g1, b1);
  k_halo<<<halo_grid(192), 256, 0, stream>>>(SLA, 192);

  // L2: 288 -> 192  (read SLB/288, write SLA/192)
  k_gemm<96, 192, 288, 2, 2, false><<<1024, 256, 0, stream>>>(SLB, A2, SLA, nullptr, nullptr, nullptr, S(1), Q(1));
  k_packip<192><<<P_TOT * 6 / 256, 256, 0, stream>>>(SLA, S(1), Q(1), g2, b2);
  k_halo<<<halo_grid(192), 256, 0, stream>>>(SLB, 192);

  // L3: 192 -> 192  (read SLA/192, write SLB/192)
  k_gemm<96, 192, 192, 2, 2, false><<<1024, 256, 0, stream>>>(SLA, A3, SLB, nullptr, nullptr, nullptr, S(2), Q(2));
  k_packip<192><<<P_TOT * 6 / 256, 256, 0, stream>>>(SLB, S(2), Q(2), g3, b3);

  // L4: 192 -> 192  (read SLB/192, write SLA/192; SLA halo already zeroed at 192 geom)
  k_gemm<96, 192, 192, 2, 2, false><<<1024, 256, 0, stream>>>(SLB, A4, SLA, nullptr, nullptr, nullptr, S(3), Q(3));
  k_halo<<<halo_grid(96), 256, 0, stream>>>(SLB, 96);

  // BN+ReLU+magnitude -> 96ch head input (read SLA/192, write SLB/96)
  k_mag<<<P_TOT * 12 / 256, 256, 0, stream>>>(SLA, S(3), Q(3), g4, b4, SLB);

  // head: 96 -> 3 (sigmoid on ch0), writes NCHW fp32 output
  k_gemm<16, 16, 96, 1, 2, true><<<512, 128, 0, stream>>>(SLB, AH, nullptr, out, bcp, bgp, nullptr, nullptr);

  (void)in_sizes; (void)n_in; (void)out_size;
}